// Round 1
// baseline (967.031 us; speedup 1.0000x reference)
//
#include <hip/hip_runtime.h>

#define EDGE_DIM   128
#define NODE_DIM   256
#define TILE_EDGES 64
#define NBLK       1024

typedef __attribute__((ext_vector_type(8))) short bf16x8;
typedef __attribute__((ext_vector_type(4))) float f32x4;

__device__ __forceinline__ unsigned short f2bf(float f) {
    unsigned u = __float_as_uint(f);
    u += 0x7fffu + ((u >> 16) & 1u);   // round-to-nearest-even
    return (unsigned short)(u >> 16);
}

__device__ __forceinline__ bf16x8 pack8(const float4 a, const float4 b) {
    bf16x8 r;
    r[0] = (short)f2bf(a.x); r[1] = (short)f2bf(a.y);
    r[2] = (short)f2bf(a.z); r[3] = (short)f2bf(a.w);
    r[4] = (short)f2bf(b.x); r[5] = (short)f2bf(b.y);
    r[6] = (short)f2bf(b.z); r[7] = (short)f2bf(b.w);
    return r;
}

// Fused: T = EF @ W^T + b  (bf16 MFMA), then atomic scatter-add to out[src], out[dst].
// Block = 256 thr (4 waves). Wave w owns columns [64w, 64w+64): B-fragments live in
// registers for the whole kernel. Grid-stride over 64-edge tiles; EF tile staged in
// LDS as pre-packed A-fragments (bf16).
__global__ __launch_bounds__(256)
void e2n_mfma(const float* __restrict__ ef,
              const int*   __restrict__ src,
              const int*   __restrict__ dst,
              const float* __restrict__ W,     // [256][128] row-major
              const float* __restrict__ bias,  // [256]
              float*       __restrict__ out,   // [n_nodes][256]
              int ntiles)
{
    // A staging: [et(4)][kt(4)][lane(64)][8 bf16]  = 16 KB
    __shared__ short Ast[4 * 4 * 64 * 8];

    const int tid  = threadIdx.x;
    const int lane = tid & 63;
    const int wid  = tid >> 6;       // wave id = column strip, also staging kt
    const int l15  = lane & 15;
    const int lhi  = lane >> 4;

    // ---- Load persistent B fragments (this wave's 64 columns, all K) ----
    // slot (lane l, elem e) of frag(ct,kt) <- W[wid*64 + ct*16 + (l&15)][kt*32 + (l>>4)*8 + e]
    bf16x8 bfr[4][4];                // [ct][kt]
    float  bset[4];
    #pragma unroll
    for (int ct = 0; ct < 4; ++ct) {
        const int row = wid * 64 + ct * 16 + l15;
        bset[ct] = bias[row];
        #pragma unroll
        for (int kt = 0; kt < 4; ++kt) {
            const int k0 = kt * 32 + lhi * 8;
            const float4* p = (const float4*)(W + (size_t)row * EDGE_DIM + k0);
            bfr[ct][kt] = pack8(p[0], p[1]);
        }
    }

    for (int t = blockIdx.x; t < ntiles; t += gridDim.x) {
        const int e0 = t * TILE_EDGES;

        __syncthreads();   // protect previous iteration's LDS reads
        // ---- Stage A tile: thread (lane, kt=wid) covers et = 0..3 ----
        #pragma unroll
        for (int et = 0; et < 4; ++et) {
            const int edge = e0 + et * 16 + l15;
            const int k0   = wid * 32 + lhi * 8;
            const float4* p = (const float4*)(ef + (size_t)edge * EDGE_DIM + k0);
            const float4 x = p[0], y = p[1];
            *(bf16x8*)&Ast[((et * 4 + wid) * 64 + lane) * 8] = pack8(x, y);
        }
        __syncthreads();

        // ---- MFMA: acc[et][ct] over 4 K-tiles ----
        f32x4 acc[4][4];
        #pragma unroll
        for (int et = 0; et < 4; ++et)
            #pragma unroll
            for (int ct = 0; ct < 4; ++ct)
                acc[et][ct] = (f32x4){0.f, 0.f, 0.f, 0.f};

        #pragma unroll
        for (int kt = 0; kt < 4; ++kt) {
            bf16x8 a[4];
            #pragma unroll
            for (int et = 0; et < 4; ++et)
                a[et] = *(const bf16x8*)&Ast[((et * 4 + kt) * 64 + lane) * 8];
            #pragma unroll
            for (int et = 0; et < 4; ++et)
                #pragma unroll
                for (int ct = 0; ct < 4; ++ct)
                    acc[et][ct] = __builtin_amdgcn_mfma_f32_16x16x32_bf16(
                        a[et], bfr[ct][kt], acc[et][ct], 0, 0, 0);
        }

        // ---- Epilogue: bias + atomic scatter to src and dst ----
        // C/D layout (verified): col = lane&15, row = (lane>>4)*4 + reg
        #pragma unroll
        for (int et = 0; et < 4; ++et) {
            const int rbase = e0 + et * 16 + lhi * 4;
            const int4 s4 = *(const int4*)(src + rbase);
            const int4 d4 = *(const int4*)(dst + rbase);
            const int sarr[4] = {s4.x, s4.y, s4.z, s4.w};
            const int darr[4] = {d4.x, d4.y, d4.z, d4.w};
            #pragma unroll
            for (int ct = 0; ct < 4; ++ct) {
                const int col = wid * 64 + ct * 16 + l15;
                #pragma unroll
                for (int r = 0; r < 4; ++r) {
                    const float v = acc[et][ct][r] + bset[ct];
                    atomicAdd(out + (size_t)sarr[r] * NODE_DIM + col, v);
                    atomicAdd(out + (size_t)darr[r] * NODE_DIM + col, v);
                }
            }
        }
    }
}

extern "C" void kernel_launch(void* const* d_in, const int* in_sizes, int n_in,
                              void* d_out, int out_size, void* d_ws, size_t ws_size,
                              hipStream_t stream) {
    const float* ef  = (const float*)d_in[0];
    const int*   idx = (const int*)d_in[1];
    const float* W   = (const float*)d_in[3];
    const float* b   = (const float*)d_in[4];
    float* out = (float*)d_out;

    const int E = in_sizes[0] / EDGE_DIM;      // 600000
    const int n_edges_idx = in_sizes[1] / 2;   // stride between src row and dst row
    const int ntiles = E / TILE_EDGES;         // 600000/64 = 9375 exact

    (void)hipMemsetAsync(d_out, 0, (size_t)out_size * sizeof(float), stream);
    e2n_mfma<<<NBLK, 256, 0, stream>>>(ef, idx, idx + n_edges_idx, W, b, out, ntiles);
}

// Round 2
// 606.403 us; speedup vs baseline: 1.5947x; 1.5947x over previous
//
#include <hip/hip_runtime.h>

#define EDGE_DIM   128
#define NODE_DIM   256

typedef __attribute__((ext_vector_type(8))) short bf16x8;
typedef __attribute__((ext_vector_type(4))) float f32x4;

__device__ __forceinline__ unsigned short f2bf(float f) {
    unsigned u = __float_as_uint(f);
    u += 0x7fffu + ((u >> 16) & 1u);   // round-to-nearest-even
    return (unsigned short)(u >> 16);
}

__device__ __forceinline__ bf16x8 pack8(const float4 a, const float4 b) {
    bf16x8 r;
    r[0] = (short)f2bf(a.x); r[1] = (short)f2bf(a.y);
    r[2] = (short)f2bf(a.z); r[3] = (short)f2bf(a.w);
    r[4] = (short)f2bf(b.x); r[5] = (short)f2bf(b.y);
    r[6] = (short)f2bf(b.z); r[7] = (short)f2bf(b.w);
    return r;
}

// ---------------------------------------------------------------------------
// Phase 1: agg[n][0:128] += ef[e][0:128] for n in {src[e], dst[e]}  (fp32 atomics)
//          deg[n] += 1 per incidence.
// Thread t covers (e = t>>7, k = t&127): ef read fully coalesced; each
// incidence's 128 atomic dwords are contiguous (512B) -> good TCC grouping.
// ---------------------------------------------------------------------------
__global__ __launch_bounds__(256)
void scatter_agg(const float* __restrict__ ef,
                 const int*   __restrict__ src,
                 const int*   __restrict__ dst,
                 float*       __restrict__ agg,   // [rowsPad][128]
                 float*       __restrict__ deg,   // [rowsPad]
                 int nE)
{
    const long long total  = (long long)nE * EDGE_DIM;
    const long long stride = (long long)gridDim.x * blockDim.x;
    for (long long t = (long long)blockIdx.x * blockDim.x + threadIdx.x;
         t < total; t += stride) {
        const int k = (int)(t & (EDGE_DIM - 1));
        const int e = (int)(t >> 7);
        const float v = ef[t];
        const int s = src[e], d = dst[e];
        atomicAdd(agg + (size_t)s * EDGE_DIM + k, v);
        atomicAdd(agg + (size_t)d * EDGE_DIM + k, v);
        if (k == 0) {
            atomicAdd(deg + s, 1.0f);
            atomicAdd(deg + d, 1.0f);
        }
    }
}

// ---------------------------------------------------------------------------
// Phase 2: out[n][c] = sum_k W[c][k]*agg[n][k] + deg[n]*b[c]
// bf16 MFMA, 64-node tiles. Block = 256 thr (4 waves); wave w owns cols
// [64w,64w+64) with persistent B fragments. agg is zero-padded to rowsPad,
// stores guarded to n < nNodes.
// ---------------------------------------------------------------------------
__global__ __launch_bounds__(256)
void gemm_out(const float* __restrict__ agg,   // [rowsPad][128]
              const float* __restrict__ deg,   // [rowsPad]
              const float* __restrict__ W,     // [256][128]
              const float* __restrict__ bias,  // [256]
              float*       __restrict__ out,   // [nNodes][256]
              int nNodes)
{
    __shared__ short Ast[4 * 4 * 64 * 8];      // [et][kt][lane][8] bf16 = 16 KB

    const int tid  = threadIdx.x;
    const int lane = tid & 63;
    const int wid  = tid >> 6;
    const int l15  = lane & 15;
    const int lhi  = lane >> 4;

    // Persistent B fragments: frag(ct,kt) slot (l,e) <- W[wid*64+ct*16+(l&15)][kt*32+(l>>4)*8+e]
    bf16x8 bfr[4][4];
    float  bset[4];
    #pragma unroll
    for (int ct = 0; ct < 4; ++ct) {
        const int row = wid * 64 + ct * 16 + l15;
        bset[ct] = bias[row];
        #pragma unroll
        for (int kt = 0; kt < 4; ++kt) {
            const float4* p = (const float4*)(W + (size_t)row * EDGE_DIM + kt * 32 + lhi * 8);
            bfr[ct][kt] = pack8(p[0], p[1]);
        }
    }

    const int e0 = blockIdx.x * 64;

    // Stage A tile (64 agg rows -> bf16 fragments in LDS)
    #pragma unroll
    for (int et = 0; et < 4; ++et) {
        const int row = e0 + et * 16 + l15;
        const float4* p = (const float4*)(agg + (size_t)row * EDGE_DIM + wid * 32 + lhi * 8);
        *(bf16x8*)&Ast[((et * 4 + wid) * 64 + lane) * 8] = pack8(p[0], p[1]);
    }
    __syncthreads();

    f32x4 acc[4][4];
    #pragma unroll
    for (int et = 0; et < 4; ++et)
        #pragma unroll
        for (int ct = 0; ct < 4; ++ct)
            acc[et][ct] = (f32x4){0.f, 0.f, 0.f, 0.f};

    #pragma unroll
    for (int kt = 0; kt < 4; ++kt) {
        bf16x8 a[4];
        #pragma unroll
        for (int et = 0; et < 4; ++et)
            a[et] = *(const bf16x8*)&Ast[((et * 4 + kt) * 64 + lane) * 8];
        #pragma unroll
        for (int et = 0; et < 4; ++et)
            #pragma unroll
            for (int ct = 0; ct < 4; ++ct)
                acc[et][ct] = __builtin_amdgcn_mfma_f32_16x16x32_bf16(
                    a[et], bfr[ct][kt], acc[et][ct], 0, 0, 0);
    }

    // Epilogue: out = acc + deg[row]*b[col]   (C/D layout: col=lane&15, row=(lane>>4)*4+r)
    #pragma unroll
    for (int et = 0; et < 4; ++et) {
        const int rbase = e0 + et * 16 + lhi * 4;
        const float4 dg = *(const float4*)(deg + rbase);
        const float darr[4] = {dg.x, dg.y, dg.z, dg.w};
        #pragma unroll
        for (int ct = 0; ct < 4; ++ct) {
            const int col = wid * 64 + ct * 16 + l15;
            #pragma unroll
            for (int r = 0; r < 4; ++r) {
                const int row = rbase + r;
                if (row < nNodes)
                    out[(size_t)row * NODE_DIM + col] = acc[et][ct][r] + darr[r] * bset[ct];
            }
        }
    }
}

// ---------------------------------------------------------------------------
// Fallback (round-1 kernel): direct fused scatter, used only if ws too small.
// ---------------------------------------------------------------------------
__global__ __launch_bounds__(256)
void e2n_mfma(const float* __restrict__ ef,
              const int*   __restrict__ src,
              const int*   __restrict__ dst,
              const float* __restrict__ W,
              const float* __restrict__ bias,
              float*       __restrict__ out,
              int ntiles)
{
    __shared__ short Ast[4 * 4 * 64 * 8];
    const int tid  = threadIdx.x;
    const int lane = tid & 63;
    const int wid  = tid >> 6;
    const int l15  = lane & 15;
    const int lhi  = lane >> 4;

    bf16x8 bfr[4][4];
    float  bset[4];
    #pragma unroll
    for (int ct = 0; ct < 4; ++ct) {
        const int row = wid * 64 + ct * 16 + l15;
        bset[ct] = bias[row];
        #pragma unroll
        for (int kt = 0; kt < 4; ++kt) {
            const float4* p = (const float4*)(W + (size_t)row * EDGE_DIM + kt * 32 + lhi * 8);
            bfr[ct][kt] = pack8(p[0], p[1]);
        }
    }

    for (int t = blockIdx.x; t < ntiles; t += gridDim.x) {
        const int e0 = t * 64;
        __syncthreads();
        #pragma unroll
        for (int et = 0; et < 4; ++et) {
            const int edge = e0 + et * 16 + l15;
            const float4* p = (const float4*)(ef + (size_t)edge * EDGE_DIM + wid * 32 + lhi * 8);
            *(bf16x8*)&Ast[((et * 4 + wid) * 64 + lane) * 8] = pack8(p[0], p[1]);
        }
        __syncthreads();

        f32x4 acc[4][4];
        #pragma unroll
        for (int et = 0; et < 4; ++et)
            #pragma unroll
            for (int ct = 0; ct < 4; ++ct)
                acc[et][ct] = (f32x4){0.f, 0.f, 0.f, 0.f};
        #pragma unroll
        for (int kt = 0; kt < 4; ++kt) {
            bf16x8 a[4];
            #pragma unroll
            for (int et = 0; et < 4; ++et)
                a[et] = *(const bf16x8*)&Ast[((et * 4 + kt) * 64 + lane) * 8];
            #pragma unroll
            for (int et = 0; et < 4; ++et)
                #pragma unroll
                for (int ct = 0; ct < 4; ++ct)
                    acc[et][ct] = __builtin_amdgcn_mfma_f32_16x16x32_bf16(
                        a[et], bfr[ct][kt], acc[et][ct], 0, 0, 0);
        }
        #pragma unroll
        for (int et = 0; et < 4; ++et) {
            const int rbase = e0 + et * 16 + lhi * 4;
            const int4 s4 = *(const int4*)(src + rbase);
            const int4 d4 = *(const int4*)(dst + rbase);
            const int sarr[4] = {s4.x, s4.y, s4.z, s4.w};
            const int darr[4] = {d4.x, d4.y, d4.z, d4.w};
            #pragma unroll
            for (int ct = 0; ct < 4; ++ct) {
                const int col = wid * 64 + ct * 16 + l15;
                #pragma unroll
                for (int r = 0; r < 4; ++r) {
                    const float v = acc[et][ct][r] + bset[ct];
                    atomicAdd(out + (size_t)sarr[r] * NODE_DIM + col, v);
                    atomicAdd(out + (size_t)darr[r] * NODE_DIM + col, v);
                }
            }
        }
    }
}

extern "C" void kernel_launch(void* const* d_in, const int* in_sizes, int n_in,
                              void* d_out, int out_size, void* d_ws, size_t ws_size,
                              hipStream_t stream) {
    const float* ef  = (const float*)d_in[0];
    const int*   idx = (const int*)d_in[1];
    const float* W   = (const float*)d_in[3];
    const float* b   = (const float*)d_in[4];
    float* out = (float*)d_out;

    const int E    = in_sizes[0] / EDGE_DIM;   // 600000
    const int nIdx = in_sizes[1] / 2;          // stride between src and dst rows
    const int nN   = out_size / NODE_DIM;      // 50000

    const int    rowsPad  = ((nN + 63) / 64) * 64;          // 50048
    const size_t aggBytes = (size_t)rowsPad * EDGE_DIM * sizeof(float);
    const size_t degBytes = (size_t)rowsPad * sizeof(float);

    if (ws_size >= aggBytes + degBytes) {
        float* agg = (float*)d_ws;
        float* deg = (float*)((char*)d_ws + aggBytes);
        (void)hipMemsetAsync(d_ws, 0, aggBytes + degBytes, stream);
        scatter_agg<<<2048, 256, 0, stream>>>(ef, idx, idx + nIdx, agg, deg, E);
        gemm_out<<<rowsPad / 64, 256, 0, stream>>>(agg, deg, W, b, out, nN);
    } else {
        (void)hipMemsetAsync(d_out, 0, (size_t)out_size * sizeof(float), stream);
        e2n_mfma<<<1024, 256, 0, stream>>>(ef, idx, idx + nIdx, W, b, out, E / 64);
    }
}

// Round 3
// 312.073 us; speedup vs baseline: 3.0987x; 1.9431x over previous
//
#include <hip/hip_runtime.h>

#define EDGE_DIM   128
#define NODE_DIM   256

typedef __attribute__((ext_vector_type(8))) short bf16x8;
typedef __attribute__((ext_vector_type(4))) float f32x4;

__device__ __forceinline__ unsigned short f2bf(float f) {
    unsigned u = __float_as_uint(f);
    u += 0x7fffu + ((u >> 16) & 1u);   // round-to-nearest-even
    return (unsigned short)(u >> 16);
}

__device__ __forceinline__ bf16x8 pack8(const float4 a, const float4 b) {
    bf16x8 r;
    r[0] = (short)f2bf(a.x); r[1] = (short)f2bf(a.y);
    r[2] = (short)f2bf(a.z); r[3] = (short)f2bf(a.w);
    r[4] = (short)f2bf(b.x); r[5] = (short)f2bf(b.y);
    r[6] = (short)f2bf(b.z); r[7] = (short)f2bf(b.w);
    return r;
}

// ---------------------------------------------------------------------------
// 1) Degree histogram: cnt[n] += 1 per incidence (int atomics, L2-resident).
// ---------------------------------------------------------------------------
__global__ __launch_bounds__(256)
void hist_k(const int* __restrict__ src, const int* __restrict__ dst,
            int* __restrict__ cnt, int nE)
{
    int i = blockIdx.x * blockDim.x + threadIdx.x;
    const int stride = gridDim.x * blockDim.x;
    for (; i < nE; i += stride) {
        atomicAdd(cnt + src[i], 1);
        atomicAdd(cnt + dst[i], 1);
    }
}

// ---------------------------------------------------------------------------
// 2) Exclusive prefix sum of cnt[0..n) -> off[0..n). Single block, 1024 thr.
//    n must be a multiple of 4. Each thread handles int4 per chunk.
// ---------------------------------------------------------------------------
__global__ __launch_bounds__(1024)
void exscan_k(const int* __restrict__ cnt, int* __restrict__ off, int n)
{
    __shared__ int wtot[16];
    __shared__ int carry;
    const int tid = threadIdx.x, lane = tid & 63, w = tid >> 6;
    if (tid == 0) carry = 0;
    __syncthreads();
    const int n4 = n >> 2;
    for (int base = 0; base < n4; base += 1024) {
        const int idx = base + tid;
        int4 v = {0, 0, 0, 0};
        if (idx < n4) v = ((const int4*)cnt)[idx];
        const int s0 = v.x, s1 = s0 + v.y, s2 = s1 + v.z, s3 = s2 + v.w;
        // wave-inclusive scan of per-thread totals
        int sc = s3;
        #pragma unroll
        for (int d = 1; d < 64; d <<= 1) {
            int t = __shfl_up(sc, d);
            if (lane >= d) sc += t;
        }
        if (lane == 63) wtot[w] = sc;
        __syncthreads();
        if (w == 0 && lane < 16) {
            int ws = wtot[lane];
            #pragma unroll
            for (int d = 1; d < 16; d <<= 1) {
                int t = __shfl_up(ws, d);
                if (lane >= d) ws += t;
            }
            wtot[lane] = ws;   // inclusive wave totals
        }
        __syncthreads();
        const int waveoff = (w == 0) ? 0 : wtot[w - 1];
        const int myexcl = carry + waveoff + (sc - s3);
        if (idx < n4) {
            int4 o;
            o.x = myexcl; o.y = myexcl + s0; o.z = myexcl + s1; o.w = myexcl + s2;
            ((int4*)off)[idx] = o;
        }
        const int chunk_total = wtot[15];
        __syncthreads();                 // all reads of carry/wtot done
        if (tid == 0) carry += chunk_total;
        __syncthreads();
    }
}

// ---------------------------------------------------------------------------
// 3) Counting-sort fill: elist[pos] = edge id, pos via cursor atomics.
// ---------------------------------------------------------------------------
__global__ __launch_bounds__(256)
void fill_k(const int* __restrict__ src, const int* __restrict__ dst,
            int* __restrict__ cursor, int* __restrict__ elist, int nE)
{
    int i = blockIdx.x * blockDim.x + threadIdx.x;
    const int stride = gridDim.x * blockDim.x;
    for (; i < nE; i += stride) {
        const int p0 = atomicAdd(cursor + src[i], 1);
        elist[p0] = i;
        const int p1 = atomicAdd(cursor + dst[i], 1);
        elist[p1] = i;
    }
}

// ---------------------------------------------------------------------------
// 4) Gather: one wave per node row; lane owns 2 columns (float2).
//    agg[n][:] = sum over incident edges of ef[e][:]   (pure fp32, no atomics)
//    Pad rows (cnt==0) get zeros -> no agg memset needed.
// ---------------------------------------------------------------------------
__global__ __launch_bounds__(256)
void gather_k(const float* __restrict__ ef, const int* __restrict__ elist,
              const int* __restrict__ off, const int* __restrict__ cnt,
              float* __restrict__ agg, int rowsPad)
{
    const int n = blockIdx.x * 4 + (threadIdx.x >> 6);
    if (n >= rowsPad) return;
    const int lane = threadIdx.x & 63;
    const int o = off[n], c = cnt[n];
    const float* base = ef + lane * 2;

    float ax = 0.f, ay = 0.f;
    int j = 0;
    for (; j + 4 <= c; j += 4) {
        const int e0 = elist[o + j + 0];
        const int e1 = elist[o + j + 1];
        const int e2 = elist[o + j + 2];
        const int e3 = elist[o + j + 3];
        const float2 v0 = *(const float2*)(base + (size_t)e0 * EDGE_DIM);
        const float2 v1 = *(const float2*)(base + (size_t)e1 * EDGE_DIM);
        const float2 v2 = *(const float2*)(base + (size_t)e2 * EDGE_DIM);
        const float2 v3 = *(const float2*)(base + (size_t)e3 * EDGE_DIM);
        ax += (v0.x + v1.x) + (v2.x + v3.x);
        ay += (v0.y + v1.y) + (v2.y + v3.y);
    }
    for (; j < c; ++j) {
        const int e = elist[o + j];
        const float2 v = *(const float2*)(base + (size_t)e * EDGE_DIM);
        ax += v.x; ay += v.y;
    }
    float2 r; r.x = ax; r.y = ay;
    *(float2*)(agg + (size_t)n * EDGE_DIM + lane * 2) = r;
}

// ---------------------------------------------------------------------------
// 5) GEMM epilogue: out[n][c] = sum_k W[c][k]*agg[n][k] + cnt[n]*b[c]
//    bf16 MFMA, 64-node tiles, 4 waves; wave owns 64 cols, persistent B frags.
// ---------------------------------------------------------------------------
__global__ __launch_bounds__(256)
void gemm_out(const float* __restrict__ agg,   // [rowsPad][128]
              const int*   __restrict__ deg,   // [rowsPad]
              const float* __restrict__ W,     // [256][128]
              const float* __restrict__ bias,  // [256]
              float*       __restrict__ out,   // [nNodes][256]
              int nNodes)
{
    __shared__ short Ast[4 * 4 * 64 * 8];      // 16 KB

    const int tid  = threadIdx.x;
    const int lane = tid & 63;
    const int wid  = tid >> 6;
    const int l15  = lane & 15;
    const int lhi  = lane >> 4;

    bf16x8 bfr[4][4];
    float  bset[4];
    #pragma unroll
    for (int ct = 0; ct < 4; ++ct) {
        const int row = wid * 64 + ct * 16 + l15;
        bset[ct] = bias[row];
        #pragma unroll
        for (int kt = 0; kt < 4; ++kt) {
            const float4* p = (const float4*)(W + (size_t)row * EDGE_DIM + kt * 32 + lhi * 8);
            bfr[ct][kt] = pack8(p[0], p[1]);
        }
    }

    const int e0 = blockIdx.x * 64;

    #pragma unroll
    for (int et = 0; et < 4; ++et) {
        const int row = e0 + et * 16 + l15;
        const float4* p = (const float4*)(agg + (size_t)row * EDGE_DIM + wid * 32 + lhi * 8);
        *(bf16x8*)&Ast[((et * 4 + wid) * 64 + lane) * 8] = pack8(p[0], p[1]);
    }
    __syncthreads();

    f32x4 acc[4][4];
    #pragma unroll
    for (int et = 0; et < 4; ++et)
        #pragma unroll
        for (int ct = 0; ct < 4; ++ct)
            acc[et][ct] = (f32x4){0.f, 0.f, 0.f, 0.f};

    #pragma unroll
    for (int kt = 0; kt < 4; ++kt) {
        bf16x8 a[4];
        #pragma unroll
        for (int et = 0; et < 4; ++et)
            a[et] = *(const bf16x8*)&Ast[((et * 4 + kt) * 64 + lane) * 8];
        #pragma unroll
        for (int et = 0; et < 4; ++et)
            #pragma unroll
            for (int ct = 0; ct < 4; ++ct)
                acc[et][ct] = __builtin_amdgcn_mfma_f32_16x16x32_bf16(
                    a[et], bfr[ct][kt], acc[et][ct], 0, 0, 0);
    }

    // C/D layout (verified): col = lane&15, row = (lane>>4)*4 + reg
    #pragma unroll
    for (int et = 0; et < 4; ++et) {
        const int rbase = e0 + et * 16 + lhi * 4;
        const int4 dg = *(const int4*)(deg + rbase);
        const float darr[4] = {(float)dg.x, (float)dg.y, (float)dg.z, (float)dg.w};
        #pragma unroll
        for (int ct = 0; ct < 4; ++ct) {
            const int col = wid * 64 + ct * 16 + l15;
            #pragma unroll
            for (int r = 0; r < 4; ++r) {
                const int row = rbase + r;
                if (row < nNodes)
                    out[(size_t)row * NODE_DIM + col] = acc[et][ct][r] + darr[r] * bset[ct];
            }
        }
    }
}

// ---------------------------------------------------------------------------
// Fallback (round-2 path): fp32 atomic scatter into agg + int deg.
// ---------------------------------------------------------------------------
__global__ __launch_bounds__(256)
void scatter_agg(const float* __restrict__ ef,
                 const int*   __restrict__ src,
                 const int*   __restrict__ dst,
                 float*       __restrict__ agg,
                 int*         __restrict__ deg,
                 int nE)
{
    const long long total  = (long long)nE * EDGE_DIM;
    const long long stride = (long long)gridDim.x * blockDim.x;
    for (long long t = (long long)blockIdx.x * blockDim.x + threadIdx.x;
         t < total; t += stride) {
        const int k = (int)(t & (EDGE_DIM - 1));
        const int e = (int)(t >> 7);
        const float v = ef[t];
        const int s = src[e], d = dst[e];
        atomicAdd(agg + (size_t)s * EDGE_DIM + k, v);
        atomicAdd(agg + (size_t)d * EDGE_DIM + k, v);
        if (k == 0) {
            atomicAdd(deg + s, 1);
            atomicAdd(deg + d, 1);
        }
    }
}

extern "C" void kernel_launch(void* const* d_in, const int* in_sizes, int n_in,
                              void* d_out, int out_size, void* d_ws, size_t ws_size,
                              hipStream_t stream) {
    const float* ef  = (const float*)d_in[0];
    const int*   idx = (const int*)d_in[1];
    const float* W   = (const float*)d_in[3];
    const float* b   = (const float*)d_in[4];
    float* out = (float*)d_out;

    const int E    = in_sizes[0] / EDGE_DIM;   // 600000
    const int nIdx = in_sizes[1] / 2;          // stride between src and dst rows
    const int nN   = out_size / NODE_DIM;      // 50000
    const int* src = idx;
    const int* dst = idx + nIdx;

    const int rowsPad = ((nN + 63) / 64) * 64;            // 50048

    const size_t aggBytes  = (size_t)rowsPad * EDGE_DIM * sizeof(float); // 25.6 MB
    const size_t cntBytes  = (size_t)rowsPad * sizeof(int);              // 200 KB
    const size_t listBytes = (size_t)2 * E * sizeof(int);                // 4.8 MB

    char* p = (char*)d_ws;
    float* agg    = (float*)p;                 p += aggBytes;
    int*   cnt    = (int*)p;                   p += cntBytes;
    int*   off    = (int*)p;                   p += cntBytes;
    int*   cursor = (int*)p;                   p += cntBytes;
    int*   elist  = (int*)p;                   p += listBytes;
    const size_t needCSR = (size_t)(p - (char*)d_ws);

    if (ws_size >= needCSR) {
        (void)hipMemsetAsync(cnt, 0, cntBytes, stream);
        hist_k<<<2048, 256, 0, stream>>>(src, dst, cnt, E);
        exscan_k<<<1, 1024, 0, stream>>>(cnt, off, rowsPad);
        (void)hipMemcpyAsync(cursor, off, cntBytes, hipMemcpyDeviceToDevice, stream);
        fill_k<<<2048, 256, 0, stream>>>(src, dst, cursor, elist, E);
        gather_k<<<rowsPad / 4, 256, 0, stream>>>(ef, elist, off, cnt, agg, rowsPad);
        gemm_out<<<rowsPad / 64, 256, 0, stream>>>(agg, cnt, W, b, out, nN);
    } else if (ws_size >= aggBytes + cntBytes) {
        (void)hipMemsetAsync(d_ws, 0, aggBytes + cntBytes, stream);
        int* deg = (int*)((char*)d_ws + aggBytes);
        scatter_agg<<<2048, 256, 0, stream>>>(ef, src, dst, agg, deg, E);
        gemm_out<<<rowsPad / 64, 256, 0, stream>>>(agg, deg, W, b, out, nN);
    }
}